// Round 5
// baseline (107.589 us; speedup 1.0000x reference)
//
#include <hip/hip_runtime.h>
#include <hip/hip_bf16.h>

#define N_NODES 20000
#define N_EDGES 100000
#define IN_DIM  128
#define HID     64
#define LAT     32
#define EDIM    16
#define EG      4     // edge-groups (of 16 edges) per block in k_edge

typedef __attribute__((ext_vector_type(8))) short bf16x8;
typedef __attribute__((ext_vector_type(4))) float f32x4;

__device__ __forceinline__ short f2bs(float f) {
    __hip_bfloat16 b = __float2bfloat16(f);
    short s;
    __builtin_memcpy(&s, &b, 2);
    return s;
}

// ---------------------------------------------------------------------------
// Fused prep: build all bf16 transposed weight tables in ws.
//   kwT  [4096][16] : kwT[c][d]  = kw[d][c]          (65536)
//   kbb8 [4096][8]  : kb[c] replicated 8x            (32768)   (kwT+65536)
//   wT   [64][128]  : wT[o][d]   = lin_w[d][o]       (8192)
//   rootT[64][64]   : rootT[o][d]= root_w[d][o]      (4096)
//   mlvT [64][64]   : o<32 -> mu_w[k][o], else lv_w  (4096)
// ---------------------------------------------------------------------------
__global__ __launch_bounds__(256) void k_prep(
        const float* __restrict__ kw,     const float* __restrict__ kb,
        const float* __restrict__ lin_w,  const float* __restrict__ root_w,
        const float* __restrict__ mu_w,   const float* __restrict__ lv_w,
        __hip_bfloat16* __restrict__ kwT, __hip_bfloat16* __restrict__ kbb8,
        __hip_bfloat16* __restrict__ wT,  __hip_bfloat16* __restrict__ rootT,
        __hip_bfloat16* __restrict__ mlvT) {
    int i = blockIdx.x * 256 + threadIdx.x;
    if (i < 65536) {
        int c = i & 4095, d = i >> 12;
        kwT[c * EDIM + d] = __float2bfloat16(kw[d * (HID * HID) + c]);
    } else if (i < 65536 + 32768) {
        int j = i - 65536;
        kbb8[j] = __float2bfloat16(kb[j >> 3]);
    } else if (i < 65536 + 32768 + 8192) {
        int j = i - (65536 + 32768);
        int o = j >> 7, d = j & 127;
        wT[j] = __float2bfloat16(lin_w[d * HID + o]);
    } else if (i < 65536 + 32768 + 8192 + 4096) {
        int j = i - (65536 + 32768 + 8192);
        int o = j >> 6, d = j & 63;
        rootT[j] = __float2bfloat16(root_w[d * HID + o]);
    } else {
        int j = i - (65536 + 32768 + 8192 + 4096);
        int o2 = j >> 6, k = j & 63;
        mlvT[j] = __float2bfloat16(o2 < 32 ? mu_w[k * LAT + o2]
                                           : lv_w[k * LAT + (o2 - 32)]);
    }
}

// ---------------------------------------------------------------------------
// Kernel A (MFMA): h = relu(x @ lin_in_w + lin_in_b)
// ---------------------------------------------------------------------------
__global__ __launch_bounds__(256) void k_lin_mfma(
        const float* __restrict__ x, const __hip_bfloat16* __restrict__ wT,
        const float* __restrict__ lin_b, float* __restrict__ h) {
    const int n0   = blockIdx.x * 16;
    const int q    = threadIdx.x >> 6;
    const int lane = threadIdx.x & 63;
    const int col  = lane & 15, grp = lane >> 4;
    const int oo   = q * 16 + col;

    f32x4 acc = {0.f, 0.f, 0.f, 0.f};
    const float* xp = x + (size_t)(n0 + col) * IN_DIM + grp * 8;
    const __hip_bfloat16* bp = wT + (size_t)oo * IN_DIM + grp * 8;
#pragma unroll
    for (int it = 0; it < 4; ++it) {
        float4 xa = *(const float4*)(xp + it * 32);
        float4 xb = *(const float4*)(xp + it * 32 + 4);
        bf16x8 af;
        af[0] = f2bs(xa.x); af[1] = f2bs(xa.y); af[2] = f2bs(xa.z); af[3] = f2bs(xa.w);
        af[4] = f2bs(xb.x); af[5] = f2bs(xb.y); af[6] = f2bs(xb.z); af[7] = f2bs(xb.w);
        bf16x8 bfv = *(const bf16x8*)(bp + it * 32);
        acc = __builtin_amdgcn_mfma_f32_16x16x32_bf16(af, bfv, acc, 0, 0, 0);
    }
    const float bias = lin_b[oo];
#pragma unroll
    for (int j = 0; j < 4; ++j) {
        int row = grp * 4 + j;
        h[(size_t)(n0 + row) * HID + oo] = fmaxf(acc[j] + bias, 0.f);
    }
}

// ---------------------------------------------------------------------------
// Kernel B (MFMA): fused edge-MLP + message + scatter-add.
// Block = EG*16 = 64 edges, wave q = oo quarter. Per hh: ONE B-fragment load
// (kwT row / bias row, k-slot trick: k<16 = ea@kw, k=16 = bias via A=1.0),
// FOUR independent MFMAs (one per edge-group) reusing it. Epilogue per group:
// relu (v_max) + packed fma (v_pk_fma_f32) against s_hT broadcast.
// ---------------------------------------------------------------------------
__global__ __launch_bounds__(256) void k_edge(
        const int* __restrict__ ei, const float* __restrict__ ea,
        const float* __restrict__ h, const __hip_bfloat16* __restrict__ kwT,
        float* __restrict__ num, float* __restrict__ cnt) {
    __shared__ float s_hT[HID][EG * 16 + 4];   // row stride 68 floats (272B)
    __shared__ int   s_dst[EG * 16];

    const int e0   = blockIdx.x * (EG * 16);
    const int tid  = threadIdx.x;
    const int q    = tid >> 6, lane = tid & 63;
    const int col  = lane & 15, grp = lane >> 4;

    // stage h[src]^T (64 edges x 64 hh); wave-coalesced global reads
    for (int i = tid; i < EG * 16 * HID; i += 256) {
        int r = i >> 6, c = i & 63;
        int e = e0 + r; if (e >= N_EDGES) e = N_EDGES - 1;
        int src = ei[e];
        s_hT[c][r] = h[(size_t)src * HID + c];
    }
    if (tid < EG * 16) {
        int e = e0 + tid; if (e >= N_EDGES) e = N_EDGES - 1;
        s_dst[tid] = ei[N_EDGES + e];
    }
    __syncthreads();

    // A fragments (loop-invariant), one per edge-group
    bf16x8 af[EG];
#pragma unroll
    for (int g = 0; g < EG; ++g) {
        bf16x8 a = {};
        if (grp < 2) {
            int e = e0 + g * 16 + col; if (e >= N_EDGES) e = N_EDGES - 1;
            const float* ep = ea + (size_t)e * EDIM + grp * 8;
            float4 a0 = *(const float4*)ep;
            float4 a1 = *(const float4*)(ep + 4);
            a[0] = f2bs(a0.x); a[1] = f2bs(a0.y); a[2] = f2bs(a0.z); a[3] = f2bs(a0.w);
            a[4] = f2bs(a1.x); a[5] = f2bs(a1.y); a[6] = f2bs(a1.z); a[7] = f2bs(a1.w);
        } else if (grp == 2) {
            a[0] = (short)0x3F80;    // bf16(1.0) -> bias row k=16
        }
        af[g] = a;
    }

    int off, stride;
    if (grp < 2) { off = (q * 16 + col) * EDIM + grp * 8; stride = 1024; }
    else         { off = 65536 + (q * 16 + col) * 8;      stride = 512;  }

    f32x4 msg[EG];
#pragma unroll
    for (int g = 0; g < EG; ++g) msg[g] = (f32x4){0.f, 0.f, 0.f, 0.f};
    const f32x4 z4 = {0.f, 0.f, 0.f, 0.f};

#pragma unroll 2
    for (int hh = 0; hh < HID; ++hh) {
        bf16x8 bfv = *(const bf16x8*)(kwT + off);
        off += stride;
#pragma unroll
        for (int g = 0; g < EG; ++g) {
            f32x4 w  = __builtin_amdgcn_mfma_f32_16x16x32_bf16(af[g], bfv, z4,
                                                               0, 0, 0);
            f32x4 wr = __builtin_elementwise_max(w, z4);
            f32x4 hv = *(const f32x4*)&s_hT[hh][g * 16 + grp * 4];
            msg[g] += wr * hv;                 // contracts to v_pk_fma_f32
        }
    }

    // scatter (guard whole 16-edge groups; E % 16 == 0)
#pragma unroll
    for (int g = 0; g < EG; ++g) {
        if (e0 + g * 16 < N_EDGES) {
#pragma unroll
            for (int j = 0; j < 4; ++j) {
                int dst = s_dst[g * 16 + grp * 4 + j];
                atomicAdd(num + (size_t)dst * HID + q * 16 + col, msg[g][j]);
            }
        }
    }
    if (tid < EG * 16 && e0 + tid < N_EDGES)
        atomicAdd(cnt + s_dst[tid], 1.f);
}

// ---------------------------------------------------------------------------
// Kernel C (MFMA): agg/root/heads fused. Block = 16 nodes.
// ---------------------------------------------------------------------------
__global__ __launch_bounds__(256) void k_out(
        const float* __restrict__ h, const float* __restrict__ num,
        const float* __restrict__ cnt,
        const __hip_bfloat16* __restrict__ rootT, const float* __restrict__ conv_b,
        const __hip_bfloat16* __restrict__ mlvT,  const float* __restrict__ mu_b,
        const float* __restrict__ lv_b, float* __restrict__ out) {
    __shared__ __align__(16) __hip_bfloat16 s_h2[16][72];
    const int n0   = blockIdx.x * 16;
    const int q    = threadIdx.x >> 6;
    const int lane = threadIdx.x & 63;
    const int col  = lane & 15, grp = lane >> 4;
    const int oo   = q * 16 + col;

    f32x4 acc = {0.f, 0.f, 0.f, 0.f};
    const float* hp = h + (size_t)(n0 + col) * HID + grp * 8;
    const __hip_bfloat16* bp = rootT + (size_t)oo * HID + grp * 8;
#pragma unroll
    for (int it = 0; it < 2; ++it) {
        float4 xa = *(const float4*)(hp + it * 32);
        float4 xb = *(const float4*)(hp + it * 32 + 4);
        bf16x8 af;
        af[0] = f2bs(xa.x); af[1] = f2bs(xa.y); af[2] = f2bs(xa.z); af[3] = f2bs(xa.w);
        af[4] = f2bs(xb.x); af[5] = f2bs(xb.y); af[6] = f2bs(xb.z); af[7] = f2bs(xb.w);
        bf16x8 bfv = *(const bf16x8*)(bp + it * 32);
        acc = __builtin_amdgcn_mfma_f32_16x16x32_bf16(af, bfv, acc, 0, 0, 0);
    }
    const float cb = conv_b[oo];
#pragma unroll
    for (int j = 0; j < 4; ++j) {
        int row = grp * 4 + j;
        int n = n0 + row;
        float agg = num[(size_t)n * HID + oo] / fmaxf(cnt[n], 1.f);
        s_h2[row][oo] = __float2bfloat16(fmaxf(acc[j] + agg + cb, 0.f));
    }
    __syncthreads();

    f32x4 acc2 = {0.f, 0.f, 0.f, 0.f};
    const __hip_bfloat16* b2 = mlvT + (size_t)oo * HID + grp * 8;
#pragma unroll
    for (int it = 0; it < 2; ++it) {
        bf16x8 af = *(const bf16x8*)((const char*)&s_h2[col][0] + it * 64 + grp * 16);
        bf16x8 bfv = *(const bf16x8*)(b2 + it * 32);
        acc2 = __builtin_amdgcn_mfma_f32_16x16x32_bf16(af, bfv, acc2, 0, 0, 0);
    }
    const float bias = (oo < 32) ? mu_b[oo] : lv_b[oo - 32];
    float* obase = (oo < 32) ? (out + oo) : (out + (size_t)N_NODES * LAT + (oo - 32));
#pragma unroll
    for (int j = 0; j < 4; ++j) {
        int n = n0 + grp * 4 + j;
        obase[(size_t)n * LAT] = acc2[j] + bias;
    }
}

// ---------------------------------------------------------------------------
extern "C" void kernel_launch(void* const* d_in, const int* in_sizes, int n_in,
                              void* d_out, int out_size, void* d_ws, size_t ws_size,
                              hipStream_t stream) {
    const float* x      = (const float*)d_in[0];
    const int*   ei     = (const int*)  d_in[1];
    const float* ea     = (const float*)d_in[2];
    const float* lin_w  = (const float*)d_in[3];
    const float* lin_b  = (const float*)d_in[4];
    const float* kw     = (const float*)d_in[5];
    const float* kb     = (const float*)d_in[6];
    const float* root_w = (const float*)d_in[7];
    const float* conv_b = (const float*)d_in[8];
    const float* mu_w   = (const float*)d_in[9];
    const float* mu_b   = (const float*)d_in[10];
    const float* lv_w   = (const float*)d_in[11];
    const float* lv_b   = (const float*)d_in[12];
    float* out = (float*)d_out;

    float* h   = (float*)d_ws;
    float* num = h   + (size_t)N_NODES * HID;
    float* cnt = num + (size_t)N_NODES * HID;
    __hip_bfloat16* kwT   = (__hip_bfloat16*)(cnt + N_NODES);  // 65536
    __hip_bfloat16* kbb8  = kwT   + 65536;                     // 32768
    __hip_bfloat16* wT    = kbb8  + 32768;                     // 8192
    __hip_bfloat16* rootT = wT    + 8192;                      // 4096
    __hip_bfloat16* mlvT  = rootT + 4096;                      // 4096

    hipMemsetAsync(num, 0, (size_t)(N_NODES * HID + N_NODES) * sizeof(float),
                   stream);

    k_prep<<<448, 256, 0, stream>>>(kw, kb, lin_w, root_w, mu_w, lv_w,
                                    kwT, kbb8, wT, rootT, mlvT);

    k_lin_mfma<<<N_NODES / 16, 256, 0, stream>>>(x, wT, lin_b, h);

    const int ngrp    = N_EDGES / 16;                 // 6250
    const int nblocks = (ngrp + EG - 1) / EG;         // 1563
    k_edge<<<nblocks, 256, 0, stream>>>(ei, ea, h, kwT, num, cnt);

    k_out<<<N_NODES / 16, 256, 0, stream>>>(h, num, cnt, rootT, conv_b,
                                            mlvT, mu_b, lv_b, out);
}